// Round 4
// baseline (819.895 us; speedup 1.0000x reference)
//
#include <hip/hip_runtime.h>
#include <hip/hip_bf16.h>

#define TQ 2048
#define TKV 2048
#define NH 16
#define HD 64
#define DM 1024
#define BSZ 4
#define LOG2E 1.44269504088896340736f

typedef __bf16 bf16_t;
typedef bf16_t bf16x8 __attribute__((ext_vector_type(8)));
typedef bf16_t bf16x4 __attribute__((ext_vector_type(4)));
typedef float f32x4 __attribute__((ext_vector_type(4)));

__device__ __forceinline__ f32x4 MFMA16(bf16x8 a, bf16x8 b, f32x4 c) {
  return __builtin_amdgcn_mfma_f32_16x16x32_bf16(a, b, c, 0, 0, 0);
}

__device__ __forceinline__ void gload_lds16(const void* g, void* l) {
  __builtin_amdgcn_global_load_lds((const __attribute__((address_space(1))) void*)g,
                                   (__attribute__((address_space(3))) void*)l,
                                   16, 0, 0);
}

// Pl logical [q][k], 16x64 per wave; swizzle keeps b128 reads ~2-way (free)
__device__ __forceinline__ int pl_idx(int q, int k) {
  int bb = (k >> 3) ^ (q & 7);
  return q * 64 + bb * 8 + (k & 7);
}

// ---------------- fused fp32->bf16 conversion + kpad additive mask ---------
__global__ __launch_bounds__(256) void cvt_all(
    const float* __restrict__ xq, const float* __restrict__ xkv,
    const float* __restrict__ wq, const float* __restrict__ wk,
    const float* __restrict__ wv, const float* __restrict__ wo,
    const unsigned char* __restrict__ kpad,
    bf16_t* __restrict__ oxq, bf16_t* __restrict__ oxkv,
    bf16_t* __restrict__ owq, bf16_t* __restrict__ owk,
    bf16_t* __restrict__ owv, bf16_t* __restrict__ owo,
    bf16_t* __restrict__ okpd) {
  const int blk = blockIdx.x;
  if (blk >= 10240) {  // kpad: B*TKV bools -> additive bf16 (-inf / 0)
    const int i = (blk - 10240) * 256 + threadIdx.x;  // 1024 threads x 8 elems
    unsigned long long bits = *reinterpret_cast<const unsigned long long*>(kpad + (size_t)i * 8);
    bf16x8 o;
#pragma unroll
    for (int j = 0; j < 8; ++j)
      o[j] = ((bits >> (8 * j)) & 0xffull) ? (bf16_t)(-__builtin_inff()) : (bf16_t)0.f;
    reinterpret_cast<bf16x8*>(okpd)[i] = o;
    return;
  }
  const float* src;
  bf16_t* dst;
  int base;
  if (blk < 4096)      { src = xq;  dst = oxq;  base = blk; }
  else if (blk < 8192) { src = xkv; dst = oxkv; base = blk - 4096; }
  else if (blk < 8704) { src = wq;  dst = owq;  base = blk - 8192; }
  else if (blk < 9216) { src = wk;  dst = owk;  base = blk - 8704; }
  else if (blk < 9728) { src = wv;  dst = owv;  base = blk - 9216; }
  else                 { src = wo;  dst = owo;  base = blk - 9728; }
  const int i = base * 256 + threadIdx.x;
  const float4* p = reinterpret_cast<const float4*>(src) + 2 * (size_t)i;
  float4 a = p[0], b = p[1];
  bf16x8 o;
  o[0] = (bf16_t)a.x; o[1] = (bf16_t)a.y; o[2] = (bf16_t)a.z; o[3] = (bf16_t)a.w;
  o[4] = (bf16_t)b.x; o[5] = (bf16_t)b.y; o[6] = (bf16_t)b.z; o[7] = (bf16_t)b.w;
  reinterpret_cast<bf16x8*>(dst)[i] = o;
}

// ---------------- attn_mask: transpose + bf16 + fold log2e -----------------
__global__ __launch_bounds__(256) void tmask(const float* __restrict__ am,
                                             bf16_t* __restrict__ amt) {
  __shared__ float T[64][65];
  const int q0 = blockIdx.x * 64, k0 = blockIdx.y * 64;
  const int tid = threadIdx.x;
  const int r = tid >> 2, c4 = (tid & 3) * 4;
#pragma unroll
  for (int cc = 0; cc < 4; ++cc) {
    const int kc = c4 + cc * 16;
    float4 v = *reinterpret_cast<const float4*>(am + (long)(q0 + r) * TKV + k0 + kc);
    T[kc + 0][r] = v.x; T[kc + 1][r] = v.y; T[kc + 2][r] = v.z; T[kc + 3][r] = v.w;
  }
  __syncthreads();
  const int kr = tid >> 2, qc0 = (tid & 3) * 16;
  bf16x8 o0, o1;
#pragma unroll
  for (int j = 0; j < 8; ++j) o0[j] = (bf16_t)(T[kr][qc0 + j] * LOG2E);
#pragma unroll
  for (int j = 0; j < 8; ++j) o1[j] = (bf16_t)(T[kr][qc0 + 8 + j] * LOG2E);
  *reinterpret_cast<bf16x8*>(amt + (long)(k0 + kr) * TQ + q0 + qc0) = o0;
  *reinterpret_cast<bf16x8*>(amt + (long)(k0 + kr) * TQ + q0 + qc0 + 8) = o1;
}

// ---------------- bt-GEMM: C[M,N] = A[M,K] * B[N,K]^T  (m97 structure) ----
template <bool BF16_OUT>
__global__ __launch_bounds__(256) void gemm_bt(const bf16_t* __restrict__ A,
                                               const bf16_t* __restrict__ Bw,
                                               void* __restrict__ Cout,
                                               int M, int N, int K, float scale) {
  __shared__ __align__(16) bf16_t As[128 * 32];
  __shared__ __align__(16) bf16_t Bs[128 * 32];
  const int tid = threadIdx.x;
  const int l = tid & 63;
  const int w = tid >> 6;
  const int wr = w >> 1, wc = w & 1;
  const int l15 = l & 15, lg = l >> 4;
  const long bm = (long)blockIdx.x * 128;
  const long bn = (long)blockIdx.y * 128;

  f32x4 acc[4][4] = {};
  const int c0i = tid, c1i = 256 + tid;
  const long ar0 = (bm + (c0i >> 2)) * (long)K + (c0i & 3) * 8;
  const long ar1 = (bm + (c1i >> 2)) * (long)K + (c1i & 3) * 8;
  const long br0 = (bn + (c0i >> 2)) * (long)K + (c0i & 3) * 8;
  const long br1 = (bn + (c1i >> 2)) * (long)K + (c1i & 3) * 8;

  for (int k0 = 0; k0 < K; k0 += 32) {
    __syncthreads();
    gload_lds16(A + ar0 + k0, As + c0i * 8);
    gload_lds16(A + ar1 + k0, As + c1i * 8);
    gload_lds16(Bw + br0 + k0, Bs + c0i * 8);
    gload_lds16(Bw + br1 + k0, Bs + c1i * 8);
    __syncthreads();

    bf16x8 af[4], bfr[4];
#pragma unroll
    for (int i = 0; i < 4; ++i)
      af[i] = *reinterpret_cast<const bf16x8*>(As + (wr * 64 + i * 16 + l15) * 32 + lg * 8);
#pragma unroll
    for (int j = 0; j < 4; ++j)
      bfr[j] = *reinterpret_cast<const bf16x8*>(Bs + (wc * 64 + j * 16 + l15) * 32 + lg * 8);
#pragma unroll
    for (int i = 0; i < 4; ++i)
#pragma unroll
      for (int j = 0; j < 4; ++j)
        acc[i][j] = MFMA16(af[i], bfr[j], acc[i][j]);
  }

  // C/D layout: col = lane&15, row = (lane>>4)*4 + reg  [m89-verified]
#pragma unroll
  for (int i = 0; i < 4; ++i)
#pragma unroll
    for (int j = 0; j < 4; ++j)
#pragma unroll
      for (int r = 0; r < 4; ++r) {
        long rg = bm + wr * 64 + i * 16 + lg * 4 + r;
        long cg = bn + wc * 64 + j * 16 + l15;
        float v = acc[i][j][r] * scale;
        if (BF16_OUT) ((bf16_t*)Cout)[rg * N + cg] = (bf16_t)v;
        else          ((float*)Cout)[rg * N + cg] = v;
      }
}

// ---------------- fused K|V projection; V written TRANSPOSED ---------------
// B = [Wk;Wv] (2048 rows x 1024). bn<1024 -> K half -> Kb[t][d] (ld 1024).
// bn>=1024 -> V half -> VT[b*1024 + d][t] (ld 2048), 4 rows packed per 8B store.
__global__ __launch_bounds__(256) void gemm_kv(const bf16_t* __restrict__ A,
                                               const bf16_t* __restrict__ Bw,
                                               bf16_t* __restrict__ Kb,
                                               bf16_t* __restrict__ VTb) {
  __shared__ __align__(16) bf16_t As[128 * 32];
  __shared__ __align__(16) bf16_t Bs[128 * 32];
  const int K = DM;
  const int tid = threadIdx.x;
  const int l = tid & 63;
  const int w = tid >> 6;
  const int wr = w >> 1, wc = w & 1;
  const int l15 = l & 15, lg = l >> 4;
  const long bm = (long)blockIdx.x * 128;
  const long bn = (long)blockIdx.y * 128;

  f32x4 acc[4][4] = {};
  const int c0i = tid, c1i = 256 + tid;
  const long ar0 = (bm + (c0i >> 2)) * (long)K + (c0i & 3) * 8;
  const long ar1 = (bm + (c1i >> 2)) * (long)K + (c1i & 3) * 8;
  const long br0 = (bn + (c0i >> 2)) * (long)K + (c0i & 3) * 8;
  const long br1 = (bn + (c1i >> 2)) * (long)K + (c1i & 3) * 8;

  for (int k0 = 0; k0 < K; k0 += 32) {
    __syncthreads();
    gload_lds16(A + ar0 + k0, As + c0i * 8);
    gload_lds16(A + ar1 + k0, As + c1i * 8);
    gload_lds16(Bw + br0 + k0, Bs + c0i * 8);
    gload_lds16(Bw + br1 + k0, Bs + c1i * 8);
    __syncthreads();

    bf16x8 af[4], bfr[4];
#pragma unroll
    for (int i = 0; i < 4; ++i)
      af[i] = *reinterpret_cast<const bf16x8*>(As + (wr * 64 + i * 16 + l15) * 32 + lg * 8);
#pragma unroll
    for (int j = 0; j < 4; ++j)
      bfr[j] = *reinterpret_cast<const bf16x8*>(Bs + (wc * 64 + j * 16 + l15) * 32 + lg * 8);
#pragma unroll
    for (int i = 0; i < 4; ++i)
#pragma unroll
      for (int j = 0; j < 4; ++j)
        acc[i][j] = MFMA16(af[i], bfr[j], acc[i][j]);
  }

  if (bn < 1024) {  // K half: row-major stores
#pragma unroll
    for (int i = 0; i < 4; ++i)
#pragma unroll
      for (int j = 0; j < 4; ++j)
#pragma unroll
        for (int r = 0; r < 4; ++r) {
          long rg = bm + wr * 64 + i * 16 + lg * 4 + r;
          long cg = bn + wc * 64 + j * 16 + l15;
          Kb[rg * DM + cg] = (bf16_t)acc[i][j][r];
        }
  } else {  // V half: transposed, 4 consecutive t per lane -> one 8B store
    const long brow = (bm >> 11) * (long)DM;  // b * 1024
    const long t0 = (bm & 2047);
#pragma unroll
    for (int i = 0; i < 4; ++i)
#pragma unroll
      for (int j = 0; j < 4; ++j) {
        long d = bn - 1024 + wc * 64 + j * 16 + l15;
        long t = t0 + wr * 64 + i * 16 + lg * 4;
        bf16x4 pk;
#pragma unroll
        for (int r = 0; r < 4; ++r) pk[r] = (bf16_t)acc[i][j][r];
        *reinterpret_cast<bf16x4*>(VTb + (brow + d) * TKV + t) = pk;
      }
  }
}

// ---------------- flash attention (barrier-free) ---------------------------
// grid (TQ/64, B*NH); 256 threads = 4 independent waves; wave owns 16 q-rows.
// KV tile 64. Q pre-scaled by 0.125*log2e; softmax in base 2.
// K from global [t][d]; V from global VT[b*1024+d][t] (both L2-resident).
__global__ __launch_bounds__(256) void attn_fwd(const bf16_t* __restrict__ Qb,
                                                const bf16_t* __restrict__ Kb,
                                                const bf16_t* __restrict__ VTb,
                                                const bf16_t* __restrict__ amt,
                                                const bf16_t* __restrict__ kpd,
                                                bf16_t* __restrict__ Ob) {
  __shared__ __align__(16) bf16_t Pl[4][16 * 64];  // per-wave P, swizzled (8 KB)
  const int tid = threadIdx.x;
  const int w = tid >> 6, l = tid & 63;
  const int l15 = l & 15, lg = l >> 4;
  const int b = blockIdx.y >> 4, h = blockIdx.y & 15;
  const int q0 = blockIdx.x * 64 + w * 16;
  const long qbase = (long)b * TQ * DM;

  const bf16_t* qp = Qb + qbase + (long)(q0 + l15) * DM + h * HD + lg * 8;
  bf16x8 qf0 = *reinterpret_cast<const bf16x8*>(qp);
  bf16x8 qf1 = *reinterpret_cast<const bf16x8*>(qp + 32);

  const bf16_t* kbase = Kb + qbase + h * HD;
  const bf16_t* vbase = VTb + ((long)b * DM + h * HD) * (long)TKV;

  f32x4 o[4] = {};
  float m[4], ls[4];
#pragma unroll
  for (int r = 0; r < 4; ++r) { m[r] = -1e30f; ls[r] = 0.f; }

  for (int k0 = 0; k0 < TKV; k0 += 64) {
    // hoisted masks: amt gives all 4 q-rows per lane in one 8B load
    bf16x4 mt[4];
    float kpf[4];
#pragma unroll
    for (int f = 0; f < 4; ++f) {
      mt[f] = *reinterpret_cast<const bf16x4*>(amt + (long)(k0 + 16 * f + l15) * TQ + q0 + lg * 4);
      kpf[f] = (float)kpd[b * TKV + k0 + 16 * f + l15];
    }

    // QK^T: 4 C-frags (16q x 64k), K direct from global
    f32x4 c[4] = {};
#pragma unroll
    for (int f = 0; f < 4; ++f) {
      const bf16_t* kp = kbase + (long)(k0 + 16 * f + l15) * DM + lg * 8;
      c[f] = MFMA16(qf0, *reinterpret_cast<const bf16x8*>(kp), c[f]);
      c[f] = MFMA16(qf1, *reinterpret_cast<const bf16x8*>(kp + 32), c[f]);
    }

    // online softmax (base 2); per-lane partial ls (no per-tile sum reduce)
#pragma unroll
    for (int r = 0; r < 4; ++r) {
      float s0 = c[0][r] + (float)mt[0][r] + kpf[0];
      float s1 = c[1][r] + (float)mt[1][r] + kpf[1];
      float s2 = c[2][r] + (float)mt[2][r] + kpf[2];
      float s3 = c[3][r] + (float)mt[3][r] + kpf[3];
      float rmax = fmaxf(fmaxf(s0, s1), fmaxf(s2, s3));
#pragma unroll
      for (int d = 1; d < 16; d <<= 1) rmax = fmaxf(rmax, __shfl_xor(rmax, d, 64));
      const float mn = fmaxf(m[r], rmax);
      const float fac = exp2f(m[r] - mn);
      m[r] = mn;
      const float p0 = exp2f(s0 - mn);
      const float p1 = exp2f(s1 - mn);
      const float p2 = exp2f(s2 - mn);
      const float p3 = exp2f(s3 - mn);
      ls[r] = ls[r] * fac + (p0 + p1 + p2 + p3);
      o[0][r] *= fac; o[1][r] *= fac; o[2][r] *= fac; o[3][r] *= fac;
      const int q = lg * 4 + r;
      Pl[w][pl_idx(q, l15)]      = (bf16_t)p0;
      Pl[w][pl_idx(q, 16 + l15)] = (bf16_t)p1;
      Pl[w][pl_idx(q, 32 + l15)] = (bf16_t)p2;
      Pl[w][pl_idx(q, 48 + l15)] = (bf16_t)p3;
    }

    // PV: o[f] += P(16x64) * VT-frags direct from global (b128 contiguous)
#pragma unroll
    for (int hh = 0; hh < 2; ++hh) {
      bf16x8 pf = *reinterpret_cast<const bf16x8*>(&Pl[w][pl_idx(l15, hh * 32 + lg * 8)]);
#pragma unroll
      for (int f = 0; f < 4; ++f) {
        const bf16_t* vp = vbase + (long)(16 * f + l15) * TKV + k0 + hh * 32 + lg * 8;
        o[f] = MFMA16(pf, *reinterpret_cast<const bf16x8*>(vp), o[f]);
      }
    }
  }

  // final: one sum-reduce of per-lane ls partials, normalize, write
#pragma unroll
  for (int r = 0; r < 4; ++r) {
    float t = ls[r];
#pragma unroll
    for (int d = 1; d < 16; d <<= 1) t += __shfl_xor(t, d, 64);
    const float inv = t > 0.f ? 1.f / t : 0.f;
    const long qg = q0 + lg * 4 + r;
    bf16_t* op = Ob + qbase + qg * DM + h * HD;
    op[l15]      = (bf16_t)(o[0][r] * inv);
    op[16 + l15] = (bf16_t)(o[1][r] * inv);
    op[32 + l15] = (bf16_t)(o[2][r] * inv);
    op[48 + l15] = (bf16_t)(o[3][r] * inv);
  }
}

// ---------------- launch ---------------------------------------------------
extern "C" void kernel_launch(void* const* d_in, const int* in_sizes, int n_in,
                              void* d_out, int out_size, void* d_ws, size_t ws_size,
                              hipStream_t stream) {
  const float* x_q = (const float*)d_in[0];
  const float* x_kv = (const float*)d_in[1];
  const float* amask = (const float*)d_in[2];
  const unsigned char* kpad = (const unsigned char*)d_in[3];
  const float* Wq = (const float*)d_in[4];
  const float* Wk = (const float*)d_in[5];
  const float* Wv = (const float*)d_in[6];
  const float* Wo = (const float*)d_in[7];
  float* out = (float*)d_out;

  char* ws = (char*)d_ws;
  const size_t MB = 1024ull * 1024ull;
  bf16_t* Ob    = (bf16_t*)(ws + 0 * MB);    // aliases xq_b (dead after Q-proj)
  bf16_t* xq_b  = (bf16_t*)(ws + 0 * MB);
  bf16_t* xkv_b = (bf16_t*)(ws + 16 * MB);
  bf16_t* Qb    = (bf16_t*)(ws + 32 * MB);
  bf16_t* Kb    = (bf16_t*)(ws + 48 * MB);
  bf16_t* VTb   = (bf16_t*)(ws + 64 * MB);   // [b*1024+d][t] 16 MB
  bf16_t* amt   = (bf16_t*)(ws + 80 * MB);   // [k][q] bf16, 8 MB
  bf16_t* Wq_b  = (bf16_t*)(ws + 88 * MB);
  bf16_t* Wk_b  = (bf16_t*)(ws + 90 * MB);   // Wk|Wv contiguous (fused KV GEMM)
  bf16_t* Wv_b  = (bf16_t*)(ws + 92 * MB);
  bf16_t* Wo_b  = (bf16_t*)(ws + 94 * MB);
  bf16_t* kpdd  = (bf16_t*)(ws + 96 * MB);   // 16 KB

  const int NTOK = BSZ * TQ;  // 8192

  cvt_all<<<10244, 256, 0, stream>>>(x_q, x_kv, Wq, Wk, Wv, Wo, kpad,
                                     xq_b, xkv_b, Wq_b, Wk_b, Wv_b, Wo_b, kpdd);
  tmask<<<dim3(TQ / 64, TKV / 64), 256, 0, stream>>>(amask, amt);

  // Q projection: fold 1/sqrt(64) * log2e
  gemm_bt<true><<<dim3(NTOK / 128, DM / 128), 256, 0, stream>>>(
      xq_b, Wq_b, Qb, NTOK, DM, DM, 0.125f * LOG2E);
  // fused K|V projection, V written transposed
  gemm_kv<<<dim3(NTOK / 128, 2 * DM / 128), 256, 0, stream>>>(xkv_b, Wk_b, Kb, VTb);

  attn_fwd<<<dim3(TQ / 64, BSZ * NH), 256, 0, stream>>>(Qb, Kb, VTb, amt, kpdd, Ob);

  gemm_bt<false><<<dim3(NTOK / 128, DM / 128), 256, 0, stream>>>(
      Ob, Wo_b, out, NTOK, DM, DM, 1.f);
}

// Round 5
// 557.150 us; speedup vs baseline: 1.4716x; 1.4716x over previous
//
#include <hip/hip_runtime.h>
#include <hip/hip_bf16.h>

#define TQ 2048
#define TKV 2048
#define NH 16
#define HD 64
#define DM 1024
#define BSZ 4
#define LOG2E 1.44269504088896340736f

typedef __bf16 bf16_t;
typedef bf16_t bf16x8 __attribute__((ext_vector_type(8)));
typedef bf16_t bf16x4 __attribute__((ext_vector_type(4)));
typedef float f32x4 __attribute__((ext_vector_type(4)));

__device__ __forceinline__ f32x4 MFMA16(bf16x8 a, bf16x8 b, f32x4 c) {
  return __builtin_amdgcn_mfma_f32_16x16x32_bf16(a, b, c, 0, 0, 0);
}

__device__ __forceinline__ void gload_lds16(const void* g, void* l) {
  __builtin_amdgcn_global_load_lds((const __attribute__((address_space(1))) void*)g,
                                   (__attribute__((address_space(3))) void*)l,
                                   16, 0, 0);
}

// Pl logical [q][k], 16x64 per wave; swizzle keeps b128 reads ~2-way (free)
__device__ __forceinline__ int pl_idx(int q, int k) {
  int bb = (k >> 3) ^ (q & 7);
  return q * 64 + bb * 8 + (k & 7);
}

// K/V LDS tiles: logical [row][c] 64x64 bf16, stored with 16B-slot swizzle:
// elem addr = row*64 + ((c>>3) ^ (row&7))*8 + (c&7).
// Reads of slot j of row r hit banks 4*(j^(r&7))..+3 -> uniform over 32 banks.
__device__ __forceinline__ int kv_idx(int row, int slot) {
  return row * 64 + (slot ^ (row & 7)) * 8;
}

// ---------------- fused fp32->bf16 conversion + kpad additive mask ---------
__global__ __launch_bounds__(256) void cvt_all(
    const float* __restrict__ xq, const float* __restrict__ xkv,
    const float* __restrict__ wq, const float* __restrict__ wk,
    const float* __restrict__ wv, const float* __restrict__ wo,
    const unsigned char* __restrict__ kpad,
    bf16_t* __restrict__ oxq, bf16_t* __restrict__ oxkv,
    bf16_t* __restrict__ owq, bf16_t* __restrict__ owk,
    bf16_t* __restrict__ owv, bf16_t* __restrict__ owo,
    bf16_t* __restrict__ okpd) {
  const int blk = blockIdx.x;
  if (blk >= 10240) {  // kpad: B*TKV bools -> additive bf16 (-inf / 0)
    const int i = (blk - 10240) * 256 + threadIdx.x;
    unsigned long long bits = *reinterpret_cast<const unsigned long long*>(kpad + (size_t)i * 8);
    bf16x8 o;
#pragma unroll
    for (int j = 0; j < 8; ++j)
      o[j] = ((bits >> (8 * j)) & 0xffull) ? (bf16_t)(-__builtin_inff()) : (bf16_t)0.f;
    reinterpret_cast<bf16x8*>(okpd)[i] = o;
    return;
  }
  const float* src;
  bf16_t* dst;
  int base;
  if (blk < 4096)      { src = xq;  dst = oxq;  base = blk; }
  else if (blk < 8192) { src = xkv; dst = oxkv; base = blk - 4096; }
  else if (blk < 8704) { src = wq;  dst = owq;  base = blk - 8192; }
  else if (blk < 9216) { src = wk;  dst = owk;  base = blk - 8704; }
  else if (blk < 9728) { src = wv;  dst = owv;  base = blk - 9216; }
  else                 { src = wo;  dst = owo;  base = blk - 9728; }
  const int i = base * 256 + threadIdx.x;
  const float4* p = reinterpret_cast<const float4*>(src) + 2 * (size_t)i;
  float4 a = p[0], b = p[1];
  bf16x8 o;
  o[0] = (bf16_t)a.x; o[1] = (bf16_t)a.y; o[2] = (bf16_t)a.z; o[3] = (bf16_t)a.w;
  o[4] = (bf16_t)b.x; o[5] = (bf16_t)b.y; o[6] = (bf16_t)b.z; o[7] = (bf16_t)b.w;
  reinterpret_cast<bf16x8*>(dst)[i] = o;
}

// ---------------- attn_mask: transpose + bf16 + fold log2e -----------------
__global__ __launch_bounds__(256) void tmask(const float* __restrict__ am,
                                             bf16_t* __restrict__ amt) {
  __shared__ float T[64][65];
  const int q0 = blockIdx.x * 64, k0 = blockIdx.y * 64;
  const int tid = threadIdx.x;
  const int r = tid >> 2, c4 = (tid & 3) * 4;
#pragma unroll
  for (int cc = 0; cc < 4; ++cc) {
    const int kc = c4 + cc * 16;
    float4 v = *reinterpret_cast<const float4*>(am + (long)(q0 + r) * TKV + k0 + kc);
    T[kc + 0][r] = v.x; T[kc + 1][r] = v.y; T[kc + 2][r] = v.z; T[kc + 3][r] = v.w;
  }
  __syncthreads();
  const int kr = tid >> 2, qc0 = (tid & 3) * 16;
  bf16x8 o0, o1;
#pragma unroll
  for (int j = 0; j < 8; ++j) o0[j] = (bf16_t)(T[kr][qc0 + j] * LOG2E);
#pragma unroll
  for (int j = 0; j < 8; ++j) o1[j] = (bf16_t)(T[kr][qc0 + 8 + j] * LOG2E);
  *reinterpret_cast<bf16x8*>(amt + (long)(k0 + kr) * TQ + q0 + qc0) = o0;
  *reinterpret_cast<bf16x8*>(amt + (long)(k0 + kr) * TQ + q0 + qc0 + 8) = o1;
}

// ---------------- bt-GEMM: C[M,N] = A[M,K] * B[N,K]^T  (m97 structure) ----
template <bool BF16_OUT>
__global__ __launch_bounds__(256) void gemm_bt(const bf16_t* __restrict__ A,
                                               const bf16_t* __restrict__ Bw,
                                               void* __restrict__ Cout,
                                               int M, int N, int K, float scale) {
  __shared__ __align__(16) bf16_t As[128 * 32];
  __shared__ __align__(16) bf16_t Bs[128 * 32];
  const int tid = threadIdx.x;
  const int l = tid & 63;
  const int w = tid >> 6;
  const int wr = w >> 1, wc = w & 1;
  const int l15 = l & 15, lg = l >> 4;
  const long bm = (long)blockIdx.x * 128;
  const long bn = (long)blockIdx.y * 128;

  f32x4 acc[4][4] = {};
  const int c0i = tid, c1i = 256 + tid;
  const long ar0 = (bm + (c0i >> 2)) * (long)K + (c0i & 3) * 8;
  const long ar1 = (bm + (c1i >> 2)) * (long)K + (c1i & 3) * 8;
  const long br0 = (bn + (c0i >> 2)) * (long)K + (c0i & 3) * 8;
  const long br1 = (bn + (c1i >> 2)) * (long)K + (c1i & 3) * 8;

  for (int k0 = 0; k0 < K; k0 += 32) {
    __syncthreads();
    gload_lds16(A + ar0 + k0, As + c0i * 8);
    gload_lds16(A + ar1 + k0, As + c1i * 8);
    gload_lds16(Bw + br0 + k0, Bs + c0i * 8);
    gload_lds16(Bw + br1 + k0, Bs + c1i * 8);
    __syncthreads();

    bf16x8 af[4], bfr[4];
#pragma unroll
    for (int i = 0; i < 4; ++i)
      af[i] = *reinterpret_cast<const bf16x8*>(As + (wr * 64 + i * 16 + l15) * 32 + lg * 8);
#pragma unroll
    for (int j = 0; j < 4; ++j)
      bfr[j] = *reinterpret_cast<const bf16x8*>(Bs + (wc * 64 + j * 16 + l15) * 32 + lg * 8);
#pragma unroll
    for (int i = 0; i < 4; ++i)
#pragma unroll
      for (int j = 0; j < 4; ++j)
        acc[i][j] = MFMA16(af[i], bfr[j], acc[i][j]);
  }

  // C/D layout: col = lane&15, row = (lane>>4)*4 + reg  [m89-verified]
#pragma unroll
  for (int i = 0; i < 4; ++i)
#pragma unroll
    for (int j = 0; j < 4; ++j)
#pragma unroll
      for (int r = 0; r < 4; ++r) {
        long rg = bm + wr * 64 + i * 16 + lg * 4 + r;
        long cg = bn + wc * 64 + j * 16 + l15;
        float v = acc[i][j][r] * scale;
        if (BF16_OUT) ((bf16_t*)Cout)[rg * N + cg] = (bf16_t)v;
        else          ((float*)Cout)[rg * N + cg] = v;
      }
}

// ---------------- fused K|V projection; V written TRANSPOSED ---------------
__global__ __launch_bounds__(256) void gemm_kv(const bf16_t* __restrict__ A,
                                               const bf16_t* __restrict__ Bw,
                                               bf16_t* __restrict__ Kb,
                                               bf16_t* __restrict__ VTb) {
  __shared__ __align__(16) bf16_t As[128 * 32];
  __shared__ __align__(16) bf16_t Bs[128 * 32];
  const int K = DM;
  const int tid = threadIdx.x;
  const int l = tid & 63;
  const int w = tid >> 6;
  const int wr = w >> 1, wc = w & 1;
  const int l15 = l & 15, lg = l >> 4;
  const long bm = (long)blockIdx.x * 128;
  const long bn = (long)blockIdx.y * 128;

  f32x4 acc[4][4] = {};
  const int c0i = tid, c1i = 256 + tid;
  const long ar0 = (bm + (c0i >> 2)) * (long)K + (c0i & 3) * 8;
  const long ar1 = (bm + (c1i >> 2)) * (long)K + (c1i & 3) * 8;
  const long br0 = (bn + (c0i >> 2)) * (long)K + (c0i & 3) * 8;
  const long br1 = (bn + (c1i >> 2)) * (long)K + (c1i & 3) * 8;

  for (int k0 = 0; k0 < K; k0 += 32) {
    __syncthreads();
    gload_lds16(A + ar0 + k0, As + c0i * 8);
    gload_lds16(A + ar1 + k0, As + c1i * 8);
    gload_lds16(Bw + br0 + k0, Bs + c0i * 8);
    gload_lds16(Bw + br1 + k0, Bs + c1i * 8);
    __syncthreads();

    bf16x8 af[4], bfr[4];
#pragma unroll
    for (int i = 0; i < 4; ++i)
      af[i] = *reinterpret_cast<const bf16x8*>(As + (wr * 64 + i * 16 + l15) * 32 + lg * 8);
#pragma unroll
    for (int j = 0; j < 4; ++j)
      bfr[j] = *reinterpret_cast<const bf16x8*>(Bs + (wc * 64 + j * 16 + l15) * 32 + lg * 8);
#pragma unroll
    for (int i = 0; i < 4; ++i)
#pragma unroll
      for (int j = 0; j < 4; ++j)
        acc[i][j] = MFMA16(af[i], bfr[j], acc[i][j]);
  }

  if (bn < 1024) {  // K half: row-major stores
#pragma unroll
    for (int i = 0; i < 4; ++i)
#pragma unroll
      for (int j = 0; j < 4; ++j)
#pragma unroll
        for (int r = 0; r < 4; ++r) {
          long rg = bm + wr * 64 + i * 16 + lg * 4 + r;
          long cg = bn + wc * 64 + j * 16 + l15;
          Kb[rg * DM + cg] = (bf16_t)acc[i][j][r];
        }
  } else {  // V half: transposed, 4 consecutive t per lane -> one 8B store
    const long brow = (bm >> 11) * (long)DM;  // b * 1024
    const long t0 = (bm & 2047);
#pragma unroll
    for (int i = 0; i < 4; ++i)
#pragma unroll
      for (int j = 0; j < 4; ++j) {
        long d = bn - 1024 + wc * 64 + j * 16 + l15;
        long t = t0 + wr * 64 + i * 16 + lg * 4;
        bf16x4 pk;
#pragma unroll
        for (int r = 0; r < 4; ++r) pk[r] = (bf16_t)acc[i][j][r];
        *reinterpret_cast<bf16x4*>(VTb + (brow + d) * TKV + t) = pk;
      }
  }
}

// ---------------- flash attention (LDS K+V, depth-1 double buffer) ---------
// grid (TQ/64, B*NH); 256 threads = 4 waves; wave owns 16 q-rows. KV tile 64.
// Q pre-scaled by 0.125*log2e; softmax base 2. K staged [kv][d], V staged
// from VT global as [d][kv]; both 16B-slot swizzled (kv_idx), sourced with
// the inverse swizzle so global_load_lds' linear dest stays correct (#21).
__global__ __launch_bounds__(256) void attn_fwd(const bf16_t* __restrict__ Qb,
                                                const bf16_t* __restrict__ Kb,
                                                const bf16_t* __restrict__ VTb,
                                                const bf16_t* __restrict__ amt,
                                                const bf16_t* __restrict__ kpd,
                                                bf16_t* __restrict__ Ob) {
  __shared__ __align__(16) bf16_t Ks[2][64 * 64];  // 16 KB
  __shared__ __align__(16) bf16_t Vs[2][64 * 64];  // 16 KB
  __shared__ __align__(16) bf16_t Pl[4][16 * 64];  // 8 KB
  const int tid = threadIdx.x;
  const int w = tid >> 6, l = tid & 63;
  const int l15 = l & 15, lg = l >> 4;
  const int b = blockIdx.y >> 4, h = blockIdx.y & 15;
  const int q0 = blockIdx.x * 64 + w * 16;
  const long qbase = (long)b * TQ * DM;

  const bf16_t* qp = Qb + qbase + (long)(q0 + l15) * DM + h * HD + lg * 8;
  bf16x8 qf0 = *reinterpret_cast<const bf16x8*>(qp);
  bf16x8 qf1 = *reinterpret_cast<const bf16x8*>(qp + 32);

  const bf16_t* kg = Kb + qbase + h * HD;                        // K rows [t][1024]
  const bf16_t* vtg = VTb + ((long)b * DM + h * HD) * (long)TKV; // VT rows [d][2048]

  // staging: thread covers slots tid and tid+256; slot s -> row s>>3, pos s&7;
  // content = global 16B chunk (pos ^ (row&7)) of that row (inverse swizzle)
  const int srow0 = tid >> 3, spos0 = tid & 7;
  const int soff0 = (spos0 ^ (srow0 & 7)) * 8;
  const int srow1 = (tid + 256) >> 3, spos1 = tid & 7;
  const int soff1 = (spos1 ^ (srow1 & 7)) * 8;

  f32x4 o[4] = {};
  float m[4], ls[4];
#pragma unroll
  for (int r = 0; r < 4; ++r) { m[r] = -1e30f; ls[r] = 0.f; }

  // prologue: stage tile 0
  gload_lds16(kg + (long)srow0 * DM + soff0, &Ks[0][tid * 8]);
  gload_lds16(kg + (long)srow1 * DM + soff1, &Ks[0][(tid + 256) * 8]);
  gload_lds16(vtg + (long)srow0 * TKV + soff0, &Vs[0][tid * 8]);
  gload_lds16(vtg + (long)srow1 * TKV + soff1, &Vs[0][(tid + 256) * 8]);
  __syncthreads();

  int cur = 0;
  const int NT = TKV / 64;
  for (int t = 0; t < NT; ++t) {
    const int k0 = t * 64;
    // prefetch next tile into the other buffer (drained by end-of-loop barrier)
    if (t + 1 < NT) {
      const long kn = (long)(k0 + 64);
      gload_lds16(kg + (kn + srow0) * DM + soff0, &Ks[cur ^ 1][tid * 8]);
      gload_lds16(kg + (kn + srow1) * DM + soff1, &Ks[cur ^ 1][(tid + 256) * 8]);
      gload_lds16(vtg + (long)srow0 * TKV + kn + soff0, &Vs[cur ^ 1][tid * 8]);
      gload_lds16(vtg + (long)srow1 * TKV + kn + soff1, &Vs[cur ^ 1][(tid + 256) * 8]);
    }
    const bf16_t* Kc = Ks[cur];
    const bf16_t* Vc = Vs[cur];

    // masks (independent global loads, L2-hot)
    bf16x4 mt[4];
    float kpf[4];
#pragma unroll
    for (int f = 0; f < 4; ++f) {
      mt[f] = *reinterpret_cast<const bf16x4*>(amt + (long)(k0 + 16 * f + l15) * TQ + q0 + lg * 4);
      kpf[f] = (float)kpd[b * TKV + k0 + 16 * f + l15];
    }

    // QK^T: 4 C-frags (16q x 64k) from swizzled LDS K
    f32x4 c[4] = {};
#pragma unroll
    for (int f = 0; f < 4; ++f) {
      const int row = 16 * f + l15;
      bf16x8 ka = *reinterpret_cast<const bf16x8*>(Kc + kv_idx(row, lg));
      bf16x8 kb = *reinterpret_cast<const bf16x8*>(Kc + kv_idx(row, 4 + lg));
      c[f] = MFMA16(qf0, ka, c[f]);
      c[f] = MFMA16(qf1, kb, c[f]);
    }

    // online softmax (base 2); per-lane partial ls
#pragma unroll
    for (int r = 0; r < 4; ++r) {
      float s0 = c[0][r] + (float)mt[0][r] + kpf[0];
      float s1 = c[1][r] + (float)mt[1][r] + kpf[1];
      float s2 = c[2][r] + (float)mt[2][r] + kpf[2];
      float s3 = c[3][r] + (float)mt[3][r] + kpf[3];
      float rmax = fmaxf(fmaxf(s0, s1), fmaxf(s2, s3));
#pragma unroll
      for (int d = 1; d < 16; d <<= 1) rmax = fmaxf(rmax, __shfl_xor(rmax, d, 64));
      const float mn = fmaxf(m[r], rmax);
      const float fac = exp2f(m[r] - mn);
      m[r] = mn;
      const float p0 = exp2f(s0 - mn);
      const float p1 = exp2f(s1 - mn);
      const float p2 = exp2f(s2 - mn);
      const float p3 = exp2f(s3 - mn);
      ls[r] = ls[r] * fac + (p0 + p1 + p2 + p3);
      o[0][r] *= fac; o[1][r] *= fac; o[2][r] *= fac; o[3][r] *= fac;
      const int q = lg * 4 + r;
      Pl[w][pl_idx(q, l15)]      = (bf16_t)p0;
      Pl[w][pl_idx(q, 16 + l15)] = (bf16_t)p1;
      Pl[w][pl_idx(q, 32 + l15)] = (bf16_t)p2;
      Pl[w][pl_idx(q, 48 + l15)] = (bf16_t)p3;
    }

    // PV: o[f] += P(16x64) * V^T-frags from swizzled LDS V ([d][kv])
#pragma unroll
    for (int hh = 0; hh < 2; ++hh) {
      bf16x8 pf = *reinterpret_cast<const bf16x8*>(&Pl[w][pl_idx(l15, hh * 32 + lg * 8)]);
#pragma unroll
      for (int f = 0; f < 4; ++f) {
        const int row = 16 * f + l15;
        bf16x8 vf = *reinterpret_cast<const bf16x8*>(Vc + kv_idx(row, hh * 4 + lg));
        o[f] = MFMA16(pf, vf, o[f]);
      }
    }

    __syncthreads();  // drains prefetch vmcnt; all waves done with buf cur
    cur ^= 1;
  }

  // final: one sum-reduce of per-lane ls partials, normalize, write
#pragma unroll
  for (int r = 0; r < 4; ++r) {
    float t = ls[r];
#pragma unroll
    for (int d = 1; d < 16; d <<= 1) t += __shfl_xor(t, d, 64);
    const float inv = t > 0.f ? 1.f / t : 0.f;
    const long qg = q0 + lg * 4 + r;
    bf16_t* op = Ob + qbase + qg * DM + h * HD;
    op[l15]      = (bf16_t)(o[0][r] * inv);
    op[16 + l15] = (bf16_t)(o[1][r] * inv);
    op[32 + l15] = (bf16_t)(o[2][r] * inv);
    op[48 + l15] = (bf16_t)(o[3][r] * inv);
  }
}

// ---------------- launch ---------------------------------------------------
extern "C" void kernel_launch(void* const* d_in, const int* in_sizes, int n_in,
                              void* d_out, int out_size, void* d_ws, size_t ws_size,
                              hipStream_t stream) {
  const float* x_q = (const float*)d_in[0];
  const float* x_kv = (const float*)d_in[1];
  const float* amask = (const float*)d_in[2];
  const unsigned char* kpad = (const unsigned char*)d_in[3];
  const float* Wq = (const float*)d_in[4];
  const float* Wk = (const float*)d_in[5];
  const float* Wv = (const float*)d_in[6];
  const float* Wo = (const float*)d_in[7];
  float* out = (float*)d_out;

  char* ws = (char*)d_ws;
  const size_t MB = 1024ull * 1024ull;
  bf16_t* Ob    = (bf16_t*)(ws + 0 * MB);    // aliases xq_b (dead after Q-proj)
  bf16_t* xq_b  = (bf16_t*)(ws + 0 * MB);
  bf16_t* xkv_b = (bf16_t*)(ws + 16 * MB);
  bf16_t* Qb    = (bf16_t*)(ws + 32 * MB);
  bf16_t* Kb    = (bf16_t*)(ws + 48 * MB);
  bf16_t* VTb   = (bf16_t*)(ws + 64 * MB);   // [b*1024+d][t] 16 MB
  bf16_t* amt   = (bf16_t*)(ws + 80 * MB);   // [k][q] bf16, 8 MB
  bf16_t* Wq_b  = (bf16_t*)(ws + 88 * MB);
  bf16_t* Wk_b  = (bf16_t*)(ws + 90 * MB);   // Wk|Wv contiguous (fused KV GEMM)
  bf16_t* Wv_b  = (bf16_t*)(ws + 92 * MB);
  bf16_t* Wo_b  = (bf16_t*)(ws + 94 * MB);
  bf16_t* kpdd  = (bf16_t*)(ws + 96 * MB);   // 16 KB

  const int NTOK = BSZ * TQ;  // 8192

  cvt_all<<<10244, 256, 0, stream>>>(x_q, x_kv, Wq, Wk, Wv, Wo, kpad,
                                     xq_b, xkv_b, Wq_b, Wk_b, Wv_b, Wo_b, kpdd);
  tmask<<<dim3(TQ / 64, TKV / 64), 256, 0, stream>>>(amask, amt);

  // Q projection: fold 1/sqrt(64) * log2e
  gemm_bt<true><<<dim3(NTOK / 128, DM / 128), 256, 0, stream>>>(
      xq_b, Wq_b, Qb, NTOK, DM, DM, 0.125f * LOG2E);
  // fused K|V projection, V written transposed
  gemm_kv<<<dim3(NTOK / 128, 2 * DM / 128), 256, 0, stream>>>(xkv_b, Wk_b, Kb, VTb);

  attn_fwd<<<dim3(TQ / 64, BSZ * NH), 256, 0, stream>>>(Qb, Kb, VTb, amt, kpdd, Ob);

  gemm_bt<false><<<dim3(NTOK / 128, DM / 128), 256, 0, stream>>>(
      Ob, Wo_b, out, NTOK, DM, DM, 1.f);
}

// Round 8
// 516.632 us; speedup vs baseline: 1.5870x; 1.0784x over previous
//
#include <hip/hip_runtime.h>
#include <hip/hip_bf16.h>

#define TQ 2048
#define TKV 2048
#define NH 16
#define HD 64
#define DM 1024
#define BSZ 4
#define LOG2E 1.44269504088896340736f

typedef __bf16 bf16_t;
typedef bf16_t bf16x8 __attribute__((ext_vector_type(8)));
typedef bf16_t bf16x4 __attribute__((ext_vector_type(4)));
typedef float f32x4 __attribute__((ext_vector_type(4)));

__device__ __forceinline__ f32x4 MFMA16(bf16x8 a, bf16x8 b, f32x4 c) {
  return __builtin_amdgcn_mfma_f32_16x16x32_bf16(a, b, c, 0, 0, 0);
}

__device__ __forceinline__ void gload_lds16(const void* g, void* l) {
  __builtin_amdgcn_global_load_lds((const __attribute__((address_space(1))) void*)g,
                                   (__attribute__((address_space(3))) void*)l,
                                   16, 0, 0);
}

// Pl logical [q][k], 16x64 per wave; swizzle keeps b128 reads ~2-way (free)
__device__ __forceinline__ int pl_idx(int q, int k) {
  int bb = (k >> 3) ^ (q & 7);
  return q * 64 + bb * 8 + (k & 7);
}

// K/V LDS tiles: logical [row][c] 64x64 bf16, 16B-slot swizzle (validated r5:
// zero bank conflicts): elem addr = row*64 + ((c>>3) ^ (row&7))*8 + (c&7)
__device__ __forceinline__ int kv_idx(int row, int slot) {
  return row * 64 + (slot ^ (row & 7)) * 8;
}

// ---------------- fused fp32->bf16 conversion (8 elems/thread) -------------
__global__ __launch_bounds__(256) void cvt_all(
    const float* __restrict__ xq, const float* __restrict__ xkv,
    const float* __restrict__ wq, const float* __restrict__ wk,
    const float* __restrict__ wv, const float* __restrict__ wo,
    bf16_t* __restrict__ oxq, bf16_t* __restrict__ oxkv,
    bf16_t* __restrict__ owq, bf16_t* __restrict__ owk,
    bf16_t* __restrict__ owv, bf16_t* __restrict__ owo) {
  const int blk = blockIdx.x;
  const float* src;
  bf16_t* dst;
  int base;
  if (blk < 4096)      { src = xq;  dst = oxq;  base = blk; }
  else if (blk < 8192) { src = xkv; dst = oxkv; base = blk - 4096; }
  else if (blk < 8704) { src = wq;  dst = owq;  base = blk - 8192; }
  else if (blk < 9216) { src = wk;  dst = owk;  base = blk - 8704; }
  else if (blk < 9728) { src = wv;  dst = owv;  base = blk - 9216; }
  else                 { src = wo;  dst = owo;  base = blk - 9728; }
  const int i = base * 256 + threadIdx.x;
  const float4* p = reinterpret_cast<const float4*>(src) + 2 * (size_t)i;
  float4 a = p[0], b = p[1];
  bf16x8 o;
  o[0] = (bf16_t)a.x; o[1] = (bf16_t)a.y; o[2] = (bf16_t)a.z; o[3] = (bf16_t)a.w;
  o[4] = (bf16_t)b.x; o[5] = (bf16_t)b.y; o[6] = (bf16_t)b.z; o[7] = (bf16_t)b.w;
  reinterpret_cast<bf16x8*>(dst)[i] = o;
}

// ------- amt2[b][k][q] = amask[q][k]*log2e + (kpad[b][k] ? -inf : 0), bf16 --
__global__ __launch_bounds__(256) void tmask2(const float* __restrict__ am,
                                              const unsigned char* __restrict__ kpad,
                                              bf16_t* __restrict__ amt2) {
  __shared__ float T[64][65];
  const int q0 = blockIdx.x * 64, k0 = blockIdx.y * 64;
  const int tid = threadIdx.x;
  const int r = tid >> 2, c4 = (tid & 3) * 4;
#pragma unroll
  for (int cc = 0; cc < 4; ++cc) {
    const int kc = c4 + cc * 16;
    float4 v = *reinterpret_cast<const float4*>(am + (long)(q0 + r) * TKV + k0 + kc);
    T[kc + 0][r] = v.x; T[kc + 1][r] = v.y; T[kc + 2][r] = v.z; T[kc + 3][r] = v.w;
  }
  __syncthreads();
  const int kr = tid >> 2, qc0 = (tid & 3) * 16;
  float mk[16];
#pragma unroll
  for (int j = 0; j < 16; ++j) mk[j] = T[kr][qc0 + j] * LOG2E;
#pragma unroll
  for (int b = 0; b < BSZ; ++b) {
    const float kv = kpad[b * TKV + k0 + kr] ? -__builtin_inff() : 0.f;
    bf16x8 o0, o1;
#pragma unroll
    for (int j = 0; j < 8; ++j) o0[j] = (bf16_t)(mk[j] + kv);
#pragma unroll
    for (int j = 0; j < 8; ++j) o1[j] = (bf16_t)(mk[8 + j] + kv);
    bf16_t* dst = amt2 + ((long)b * TKV + k0 + kr) * TQ + q0 + qc0;
    *reinterpret_cast<bf16x8*>(dst) = o0;
    *reinterpret_cast<bf16x8*>(dst + 8) = o1;
  }
}

// ---------------- bt-GEMM: C[M,N] = A[M,K] * B[N,K]^T  (m97 structure) ----
template <bool BF16_OUT>
__global__ __launch_bounds__(256) void gemm_bt(const bf16_t* __restrict__ A,
                                               const bf16_t* __restrict__ Bw,
                                               void* __restrict__ Cout,
                                               int M, int N, int K, float scale) {
  __shared__ __align__(16) bf16_t As[128 * 32];
  __shared__ __align__(16) bf16_t Bs[128 * 32];
  const int tid = threadIdx.x;
  const int l = tid & 63;
  const int w = tid >> 6;
  const int wr = w >> 1, wc = w & 1;
  const int l15 = l & 15, lg = l >> 4;
  const long bm = (long)blockIdx.x * 128;
  const long bn = (long)blockIdx.y * 128;

  f32x4 acc[4][4] = {};
  const int c0i = tid, c1i = 256 + tid;
  const long ar0 = (bm + (c0i >> 2)) * (long)K + (c0i & 3) * 8;
  const long ar1 = (bm + (c1i >> 2)) * (long)K + (c1i & 3) * 8;
  const long br0 = (bn + (c0i >> 2)) * (long)K + (c0i & 3) * 8;
  const long br1 = (bn + (c1i >> 2)) * (long)K + (c1i & 3) * 8;

  for (int k0 = 0; k0 < K; k0 += 32) {
    __syncthreads();
    gload_lds16(A + ar0 + k0, As + c0i * 8);
    gload_lds16(A + ar1 + k0, As + c1i * 8);
    gload_lds16(Bw + br0 + k0, Bs + c0i * 8);
    gload_lds16(Bw + br1 + k0, Bs + c1i * 8);
    __syncthreads();

    bf16x8 af[4], bfr[4];
#pragma unroll
    for (int i = 0; i < 4; ++i)
      af[i] = *reinterpret_cast<const bf16x8*>(As + (wr * 64 + i * 16 + l15) * 32 + lg * 8);
#pragma unroll
    for (int j = 0; j < 4; ++j)
      bfr[j] = *reinterpret_cast<const bf16x8*>(Bs + (wc * 64 + j * 16 + l15) * 32 + lg * 8);
#pragma unroll
    for (int i = 0; i < 4; ++i)
#pragma unroll
      for (int j = 0; j < 4; ++j)
        acc[i][j] = MFMA16(af[i], bfr[j], acc[i][j]);
  }

  // C/D layout: col = lane&15, row = (lane>>4)*4 + reg  [m89-verified]
#pragma unroll
  for (int i = 0; i < 4; ++i)
#pragma unroll
    for (int j = 0; j < 4; ++j)
#pragma unroll
      for (int r = 0; r < 4; ++r) {
        long rg = bm + wr * 64 + i * 16 + lg * 4 + r;
        long cg = bn + wc * 64 + j * 16 + l15;
        float v = acc[i][j][r] * scale;
        if (BF16_OUT) ((bf16_t*)Cout)[rg * N + cg] = (bf16_t)v;
        else          ((float*)Cout)[rg * N + cg] = v;
      }
}

// ---------------- fused K|V projection; V written TRANSPOSED ---------------
__global__ __launch_bounds__(256) void gemm_kv(const bf16_t* __restrict__ A,
                                               const bf16_t* __restrict__ Bw,
                                               bf16_t* __restrict__ Kb,
                                               bf16_t* __restrict__ VTb) {
  __shared__ __align__(16) bf16_t As[128 * 32];
  __shared__ __align__(16) bf16_t Bs[128 * 32];
  const int K = DM;
  const int tid = threadIdx.x;
  const int l = tid & 63;
  const int w = tid >> 6;
  const int wr = w >> 1, wc = w & 1;
  const int l15 = l & 15, lg = l >> 4;
  const long bm = (long)blockIdx.x * 128;
  const long bn = (long)blockIdx.y * 128;

  f32x4 acc[4][4] = {};
  const int c0i = tid, c1i = 256 + tid;
  const long ar0 = (bm + (c0i >> 2)) * (long)K + (c0i & 3) * 8;
  const long ar1 = (bm + (c1i >> 2)) * (long)K + (c1i & 3) * 8;
  const long br0 = (bn + (c0i >> 2)) * (long)K + (c0i & 3) * 8;
  const long br1 = (bn + (c1i >> 2)) * (long)K + (c1i & 3) * 8;

  for (int k0 = 0; k0 < K; k0 += 32) {
    __syncthreads();
    gload_lds16(A + ar0 + k0, As + c0i * 8);
    gload_lds16(A + ar1 + k0, As + c1i * 8);
    gload_lds16(Bw + br0 + k0, Bs + c0i * 8);
    gload_lds16(Bw + br1 + k0, Bs + c1i * 8);
    __syncthreads();

    bf16x8 af[4], bfr[4];
#pragma unroll
    for (int i = 0; i < 4; ++i)
      af[i] = *reinterpret_cast<const bf16x8*>(As + (wr * 64 + i * 16 + l15) * 32 + lg * 8);
#pragma unroll
    for (int j = 0; j < 4; ++j)
      bfr[j] = *reinterpret_cast<const bf16x8*>(Bs + (wc * 64 + j * 16 + l15) * 32 + lg * 8);
#pragma unroll
    for (int i = 0; i < 4; ++i)
#pragma unroll
      for (int j = 0; j < 4; ++j)
        acc[i][j] = MFMA16(af[i], bfr[j], acc[i][j]);
  }

  if (bn < 1024) {  // K half: row-major stores
#pragma unroll
    for (int i = 0; i < 4; ++i)
#pragma unroll
      for (int j = 0; j < 4; ++j)
#pragma unroll
        for (int r = 0; r < 4; ++r) {
          long rg = bm + wr * 64 + i * 16 + lg * 4 + r;
          long cg = bn + wc * 64 + j * 16 + l15;
          Kb[rg * DM + cg] = (bf16_t)acc[i][j][r];
        }
  } else {  // V half: transposed, 4 consecutive t per lane -> one 8B store
    const long brow = (bm >> 11) * (long)DM;  // b * 1024
    const long t0 = (bm & 2047);
#pragma unroll
    for (int i = 0; i < 4; ++i)
#pragma unroll
      for (int j = 0; j < 4; ++j) {
        long d = bn - 1024 + wc * 64 + j * 16 + l15;
        long t = t0 + wr * 64 + i * 16 + lg * 4;
        bf16x4 pk;
#pragma unroll
        for (int r = 0; r < 4; ++r) pk[r] = (bf16_t)acc[i][j][r];
        *reinterpret_cast<bf16x4*>(VTb + (brow + d) * TKV + t) = pk;
      }
  }
}

// ---------------- flash attention: QBLK=128/block, 32 q-rows/wave ----------
// grid (16, 64) remapped XCD-chunked. 256 threads = 4 waves; wave owns 2
// q-frags (32 rows). KV tile 64, LDS dbuf (r5-validated swizzle). Softmax
// base 2; mask enters via MFMA C-init from amt2; T13 defer-rescale THR=8.
__global__ __launch_bounds__(256) void attn_fwd(const bf16_t* __restrict__ Qb,
                                                const bf16_t* __restrict__ Kb,
                                                const bf16_t* __restrict__ VTb,
                                                const bf16_t* __restrict__ amt2,
                                                bf16_t* __restrict__ Ob) {
  __shared__ __align__(16) bf16_t Ks[2][64 * 64];  // 16 KB
  __shared__ __align__(16) bf16_t Vs[2][64 * 64];  // 16 KB
  __shared__ __align__(16) bf16_t Pl[4][16 * 64];  // 8 KB (per-wave, g-reused)
  const int tid = threadIdx.x;
  const int w = tid >> 6, l = tid & 63;
  const int l15 = l & 15, lg = l >> 4;

  // XCD-chunked bijective remap: XCD k owns work ids [k*128, (k+1)*128)
  const int flat = blockIdx.y * 16 + blockIdx.x;   // 1024 = 8 * 128
  const int nid = (flat & 7) * 128 + (flat >> 3);
  const int bh = nid >> 4, qb = nid & 15;
  const int b = bh >> 4, h = bh & 15;
  const int q0 = qb * 128 + w * 32;
  const long qbase = (long)b * TQ * DM;

  // Q fragments: 2 q-frags (g), 2 k-halves each
  const bf16_t* qp = Qb + qbase + (long)(q0 + l15) * DM + h * HD + lg * 8;
  bf16x8 qf[2][2];
  qf[0][0] = *reinterpret_cast<const bf16x8*>(qp);
  qf[0][1] = *reinterpret_cast<const bf16x8*>(qp + 32);
  qf[1][0] = *reinterpret_cast<const bf16x8*>(qp + 16 * DM);
  qf[1][1] = *reinterpret_cast<const bf16x8*>(qp + 16 * DM + 32);

  const bf16_t* kg = Kb + qbase + h * HD;                        // K rows [t][1024]
  const bf16_t* vtg = VTb + ((long)b * DM + h * HD) * (long)TKV; // VT rows [d][2048]
  const bf16_t* m2 = amt2 + (long)b * TKV * TQ;                  // [k][q]

  // staging (r5-validated): thread covers slots tid, tid+256
  const int srow0 = tid >> 3;
  const int soff0 = ((tid & 7) ^ (srow0 & 7)) * 8;
  const int srow1 = (tid + 256) >> 3;
  const int soff1 = ((tid & 7) ^ (srow1 & 7)) * 8;

  f32x4 o[2][4] = {};
  float m[2][4], ls[2][4];
#pragma unroll
  for (int g = 0; g < 2; ++g)
#pragma unroll
    for (int r = 0; r < 4; ++r) { m[g][r] = -1e30f; ls[g][r] = 0.f; }

  // prologue: stage tile 0
  gload_lds16(kg + (long)srow0 * DM + soff0, &Ks[0][tid * 8]);
  gload_lds16(kg + (long)srow1 * DM + soff1, &Ks[0][(tid + 256) * 8]);
  gload_lds16(vtg + (long)srow0 * TKV + soff0, &Vs[0][tid * 8]);
  gload_lds16(vtg + (long)srow1 * TKV + soff1, &Vs[0][(tid + 256) * 8]);
  __syncthreads();

  int cur = 0;
  const int NT = TKV / 64;
  for (int t = 0; t < NT; ++t) {
    const int k0 = t * 64;
    if (t + 1 < NT) {
      const long kn = (long)(k0 + 64);
      gload_lds16(kg + (kn + srow0) * DM + soff0, &Ks[cur ^ 1][tid * 8]);
      gload_lds16(kg + (kn + srow1) * DM + soff1, &Ks[cur ^ 1][(tid + 256) * 8]);
      gload_lds16(vtg + (long)srow0 * TKV + kn + soff0, &Vs[cur ^ 1][tid * 8]);
      gload_lds16(vtg + (long)srow1 * TKV + kn + soff1, &Vs[cur ^ 1][(tid + 256) * 8]);
    }
    const bf16_t* Kc = Ks[cur];
    const bf16_t* Vc = Vs[cur];

    // mask loads (issued first; latency hides under LDS reads + MFMA)
    bf16x4 mt[2][4];
#pragma unroll
    for (int g = 0; g < 2; ++g)
#pragma unroll
      for (int f = 0; f < 4; ++f)
        mt[g][f] = *reinterpret_cast<const bf16x4*>(
            m2 + (long)(k0 + 16 * f + l15) * TQ + q0 + g * 16 + lg * 4);

    // C-init from mask (mask add costs only the cvt; MFMA accumulates on top)
    f32x4 c[2][4];
#pragma unroll
    for (int g = 0; g < 2; ++g)
#pragma unroll
      for (int f = 0; f < 4; ++f)
#pragma unroll
        for (int r = 0; r < 4; ++r) c[g][f][r] = (float)mt[g][f][r];

    // QK^T: K-frags read once, shared by both q-frags
#pragma unroll
    for (int f = 0; f < 4; ++f) {
      const int row = 16 * f + l15;
      bf16x8 ka = *reinterpret_cast<const bf16x8*>(Kc + kv_idx(row, lg));
      bf16x8 kb2 = *reinterpret_cast<const bf16x8*>(Kc + kv_idx(row, 4 + lg));
#pragma unroll
      for (int g = 0; g < 2; ++g) {
        c[g][f] = MFMA16(qf[g][0], ka, c[g][f]);
        c[g][f] = MFMA16(qf[g][1], kb2, c[g][f]);
      }
    }

    // per q-frag: online softmax + P-transpose + PV
#pragma unroll
    for (int g = 0; g < 2; ++g) {
#pragma unroll
      for (int r = 0; r < 4; ++r) {
        const float s0 = c[g][0][r], s1 = c[g][1][r];
        const float s2 = c[g][2][r], s3 = c[g][3][r];
        float rmax = fmaxf(fmaxf(s0, s1), fmaxf(s2, s3));
#pragma unroll
        for (int d = 1; d < 16; d <<= 1) rmax = fmaxf(rmax, __shfl_xor(rmax, d, 64));
        // T13 defer-rescale: P bounded by 2^8, bf16/f32 tolerate
        if (!__all(rmax <= m[g][r] + 8.f)) {
          const float mn = fmaxf(m[g][r], rmax);
          const float fac = exp2f(m[g][r] - mn);
          ls[g][r] *= fac;
          o[g][0][r] *= fac; o[g][1][r] *= fac;
          o[g][2][r] *= fac; o[g][3][r] *= fac;
          m[g][r] = mn;
        }
        const float p0 = exp2f(s0 - m[g][r]);
        const float p1 = exp2f(s1 - m[g][r]);
        const float p2 = exp2f(s2 - m[g][r]);
        const float p3 = exp2f(s3 - m[g][r]);
        ls[g][r] += (p0 + p1) + (p2 + p3);
        const int q = lg * 4 + r;
        Pl[w][pl_idx(q, l15)]      = (bf16_t)p0;
        Pl[w][pl_idx(q, 16 + l15)] = (bf16_t)p1;
        Pl[w][pl_idx(q, 32 + l15)] = (bf16_t)p2;
        Pl[w][pl_idx(q, 48 + l15)] = (bf16_t)p3;
      }
      // PV for this q-frag (Pl reused across g: own-wave data, lgkmcnt orders)
#pragma unroll
      for (int hh = 0; hh < 2; ++hh) {
        bf16x8 pf = *reinterpret_cast<const bf16x8*>(&Pl[w][pl_idx(l15, hh * 32 + lg * 8)]);
#pragma unroll
        for (int f = 0; f < 4; ++f) {
          bf16x8 vf = *reinterpret_cast<const bf16x8*>(Vc + kv_idx(16 * f + l15, hh * 4 + lg));
          o[g][f] = MFMA16(pf, vf, o[g][f]);
        }
      }
    }

    __syncthreads();  // drains prefetch vmcnt; all waves done with buf cur
    cur ^= 1;
  }

  // epilogue: reduce per-lane ls partials, normalize, write
#pragma unroll
  for (int g = 0; g < 2; ++g)
#pragma unroll
    for (int r = 0; r < 4; ++r) {
      float t = ls[g][r];
#pragma unroll
      for (int d = 1; d < 16; d <<= 1) t += __shfl_xor(t, d, 64);
      const float inv = t > 0.f ? 1.f / t : 0.f;
      const long qg = q0 + g * 16 + lg * 4 + r;
      bf16_t* op = Ob + qbase + qg * DM + h * HD;
      op[l15]      = (bf16_t)(o[g][0][r] * inv);
      op[16 + l15] = (bf16_t)(o[g][1][r] * inv);
      op[32 + l15] = (bf16_t)(o[g][2][r] * inv);
      op[48 + l15] = (bf16_t)(o[g][3][r] * inv);
    }
}

// ---------------- launch ---------------------------------------------------
extern "C" void kernel_launch(void* const* d_in, const int* in_sizes, int n_in,
                              void* d_out, int out_size, void* d_ws, size_t ws_size,
                              hipStream_t stream) {
  const float* x_q = (const float*)d_in[0];
  const float* x_kv = (const float*)d_in[1];
  const float* amask = (const float*)d_in[2];
  const unsigned char* kpad = (const unsigned char*)d_in[3];
  const float* Wq = (const float*)d_in[4];
  const float* Wk = (const float*)d_in[5];
  const float* Wv = (const float*)d_in[6];
  const float* Wo = (const float*)d_in[7];
  float* out = (float*)d_out;

  char* ws = (char*)d_ws;
  const size_t MB = 1024ull * 1024ull;
  bf16_t* xq_b  = (bf16_t*)(ws + 0 * MB);    // dead after Q-proj
  bf16_t* xkv_b = (bf16_t*)(ws + 16 * MB);   // dead after KV-proj
  bf16_t* amt2  = (bf16_t*)(ws + 0 * MB);    // 32 MB, written AFTER projections
  bf16_t* Qb    = (bf16_t*)(ws + 32 * MB);
  bf16_t* Kb    = (bf16_t*)(ws + 48 * MB);
  bf16_t* VTb   = (bf16_t*)(ws + 64 * MB);   // [b*1024+d][t]
  bf16_t* Ob    = (bf16_t*)(ws + 80 * MB);
  bf16_t* Wq_b  = (bf16_t*)(ws + 96 * MB);
  bf16_t* Wk_b  = (bf16_t*)(ws + 98 * MB);   // Wk|Wv contiguous (fused KV GEMM)
  bf16_t* Wv_b  = (bf16_t*)(ws + 100 * MB);
  bf16_t* Wo_b  = (bf16_t*)(ws + 102 * MB);  // ends at 104 MB

  const int NTOK = BSZ * TQ;  // 8192

  cvt_all<<<10240, 256, 0, stream>>>(x_q, x_kv, Wq, Wk, Wv, Wo,
                                     xq_b, xkv_b, Wq_b, Wk_b, Wv_b, Wo_b);

  // Q projection: fold 1/sqrt(64) * log2e
  gemm_bt<true><<<dim3(NTOK / 128, DM / 128), 256, 0, stream>>>(
      xq_b, Wq_b, Qb, NTOK, DM, DM, 0.125f * LOG2E);
  // fused K|V projection, V written transposed
  gemm_kv<<<dim3(NTOK / 128, 2 * DM / 128), 256, 0, stream>>>(xkv_b, Wk_b, Kb, VTb);

  // build merged mask AFTER projections (overwrites dead xq_b/xkv_b space)
  tmask2<<<dim3(TQ / 64, TKV / 64), 256, 0, stream>>>(amask, kpad, amt2);

  attn_fwd<<<dim3(16, 64), 256, 0, stream>>>(Qb, Kb, VTb, amt2, Ob);

  gemm_bt<false><<<dim3(NTOK / 128, DM / 128), 256, 0, stream>>>(
      Ob, Wo_b, out, NTOK, DM, DM, 1.f);
}